// Round 7
// baseline (348.028 us; speedup 1.0000x reference)
//
#include <hip/hip_runtime.h>
#include <math.h>

#define NIMG 4
#define NCLS 15
#define HW 65536
#define NANG 90
#define KTOP 400
#define POSTN 100
#define NBINS 4096
#define CAP 4096

// ---- workspace layout (bytes) ----
// zeroed: hist 4*4096*4=65536 | cnt 64
#define HIST_OFF   0
#define CNT_OFF    65536
#define ZERO_BYTES 65600
#define CAND_OFF   65600                  // 4*4096*8 = 131072 -> end 196672

__device__ __forceinline__ float sigmoidf(float x) {
    return 1.0f / (1.0f + expf(-x));
}

// ---------------- K1: histogram of comb scores (float4: 4 pixels/thread) ----------------
__global__ __launch_bounds__(256)
void k_hist(const float* __restrict__ cls, const float* __restrict__ ctr,
            int* __restrict__ hist) {
    __shared__ int sh[NBINS];
    const int n = blockIdx.y;
    const int p4 = (blockIdx.x * 256 + threadIdx.x) * 4;
    for (int b = threadIdx.x; b < NBINS; b += 256) sh[b] = 0;
    __syncthreads();
    float4 cv4 = *(const float4*)(ctr + n * HW + p4);
    float cv[4] = {sigmoidf(cv4.x), sigmoidf(cv4.y), sigmoidf(cv4.z), sigmoidf(cv4.w)};
    for (int j = 0; j < NCLS; ++j) {
        float4 s4 = *(const float4*)(cls + (size_t)(n * NCLS + j) * HW + p4);
        float sv[4] = {s4.x, s4.y, s4.z, s4.w};
#pragma unroll
        for (int e = 0; e < 4; ++e) {
            float s = sigmoidf(sv[e]);
            if (s > 0.05f) {
                float comb = s * cv[e];
                int b = (int)(comb * 4096.0f);
                b = b < 0 ? 0 : (b > NBINS - 1 ? NBINS - 1 : b);
                atomicAdd(&sh[b], 1);
            }
        }
    }
    __syncthreads();
    for (int b = threadIdx.x; b < NBINS; b += 256) {
        int v = sh[b];
        if (v) atomicAdd(&hist[n * NBINS + b], v);
    }
}

// ---------------- K2: per-block threshold recompute + collect (float4) ----------------
__global__ __launch_bounds__(256)
void k_collect(const float* __restrict__ cls, const float* __restrict__ ctr,
               const int* __restrict__ hist, int* __restrict__ cnt,
               unsigned long long* __restrict__ cand) {
    const int n = blockIdx.y;
    __shared__ int part[256];
    __shared__ int s_t;
    {
        const int* hb = hist + n * NBINS;
        int s = 0;
        int base = threadIdx.x * 16;
        for (int b = 0; b < 16; ++b) s += hb[base + b];
        part[threadIdx.x] = s;
        __syncthreads();
        if (threadIdx.x == 0) {
            int acc = 0, seg = -1, above = 0;
            for (int sg = 255; sg >= 0; --sg) {
                int ps = part[sg];
                if (acc + ps >= KTOP) { seg = sg; above = acc; break; }
                acc += ps;
            }
            int t = 0;
            if (seg >= 0) {
                int a2 = above;
                t = seg * 16;
                for (int b = seg * 16 + 15; b >= seg * 16; --b) {
                    a2 += hb[b];
                    if (a2 >= KTOP) { t = b; break; }
                }
            }
            s_t = t;
        }
        __syncthreads();
    }
    const int t = s_t;
    const int p4 = (blockIdx.x * 256 + threadIdx.x) * 4;
    float4 cv4 = *(const float4*)(ctr + n * HW + p4);
    float cv[4] = {sigmoidf(cv4.x), sigmoidf(cv4.y), sigmoidf(cv4.z), sigmoidf(cv4.w)};
    for (int j = 0; j < NCLS; ++j) {
        float4 s4 = *(const float4*)(cls + (size_t)(n * NCLS + j) * HW + p4);
        float sv[4] = {s4.x, s4.y, s4.z, s4.w};
#pragma unroll
        for (int e = 0; e < 4; ++e) {
            float s = sigmoidf(sv[e]);
            if (s > 0.05f) {
                float comb = s * cv[e];
                int b = (int)(comb * 4096.0f);
                b = b < 0 ? 0 : (b > NBINS - 1 ? NBINS - 1 : b);
                if (b >= t) {
                    int pos = atomicAdd(&cnt[n], 1);
                    if (pos < CAP) {
                        unsigned int fb  = __float_as_uint(comb);
                        unsigned int idx = (unsigned int)((p4 + e) * NCLS + j);
                        cand[n * CAP + pos] =
                            ((unsigned long long)fb << 32) | (unsigned long long)(~idx);
                    }
                }
            }
        }
    }
}

// ---- register-resident dynamic-index helpers (avoid scratch) ----
__device__ __forceinline__ float arr_get8(const float* a, int idx) {
    float r = a[0];
#pragma unroll
    for (int s = 1; s < 8; ++s) r = (s == idx) ? a[s] : r;
    return r;
}
__device__ __forceinline__ void arr_set8(float* a, int idx, float v) {
#pragma unroll
    for (int s = 0; s < 8; ++s) a[s] = (s == idx) ? v : a[s];
}

// ---- rotated-quad intersection (Sutherland-Hodgman, mirrors ref) ----
__device__ float quad_inter_area(const float* c1x, const float* c1y,
                                 const float* c2x, const float* c2y) {
#pragma clang fp contract(off)
    float px[8], py[8], qx[8], qy[8];
    int n = 4;
#pragma unroll
    for (int i = 0; i < 8; ++i) { px[i] = (i < 4) ? c1x[i] : 0.0f;
                                  py[i] = (i < 4) ? c1y[i] : 0.0f;
                                  qx[i] = 0.0f; qy[i] = 0.0f; }
#pragma unroll
    for (int e = 0; e < 4; ++e) {
        float p1x = c2x[e], p1y = c2y[e];
        int e2 = (e + 1) & 3;
        float ex = c2x[e2] - p1x, ey = c2y[e2] - p1y;
        int m = 0;
#pragma unroll
        for (int i = 0; i < 8; ++i) {
            if (i < n) {
                int j = (i == n - 1) ? 0 : i + 1;
                float cxi = px[i], cyi = py[i];
                float cxj = arr_get8(px, j), cyj = arr_get8(py, j);
                float dc = ex * (cyi - p1y) - ey * (cxi - p1x);
                float dn = ex * (cyj - p1y) - ey * (cxj - p1x);
                bool ic = (dc >= 0.0f), in2 = (dn >= 0.0f);
                if (ic) { arr_set8(qx, m, cxi); arr_set8(qy, m, cyi); ++m; }
                if (ic != in2) {
                    float denom = dc - dn;
                    if (fabsf(denom) < 1e-8f) denom = 1e-8f;
                    float tp = dc / denom;
                    arr_set8(qx, m, cxi + tp * (cxj - cxi));
                    arr_set8(qy, m, cyi + tp * (cyj - cyi));
                    ++m;
                }
            }
        }
        n = m;
        if (n == 0) return 0.0f;
#pragma unroll
        for (int i = 0; i < 8; ++i) { px[i] = qx[i]; py[i] = qy[i]; }
    }
    float ssum = 0.0f;
#pragma unroll
    for (int i = 0; i < 8; ++i) {
        if (i < n) {
            int j = (i == n - 1) ? 0 : i + 1;
            ssum += px[i] * arr_get8(py, j) - arr_get8(px, j) * py[i];
        }
    }
    return 0.5f * fabsf(ssum);
}

// ========== K3: fused tail — sort + decode + pairs + NMS + output ==========
// One 1024-thread block per image; all phases via block barriers, data in LDS.
__global__ __launch_bounds__(1024)
void k_tail(const unsigned long long* __restrict__ cand, const int* __restrict__ cnt,
            const float* __restrict__ reg, const float* __restrict__ ang,
            const float* __restrict__ anchors, float* __restrict__ out) {
#pragma clang fp contract(off)
    const int n = blockIdx.x;
    const int tid = threadIdx.x;

    __shared__ unsigned long long keys[CAP];        // 32 KB; reused as sup bits
    __shared__ unsigned long long s_skey[KTOP];     // sorted top-400 keys
    __shared__ float s_cor[KTOP * 8];
    __shared__ float s_cx[KTOP], s_cy[KTOP], s_rad[KTOP], s_area[KTOP], s_sc[KTOP];
    __shared__ int   s_lab[KTOP], s_val[KTOP];
    __shared__ int   s_order[POSTN];
    __shared__ int   s_kcnt;
    unsigned int* sup32 = (unsigned int*)keys;      // 7*7*64*2 = 6272 uints (25 KB)

    // ---------- P1: bitonic sort -> top-400 ----------
    int c = cnt[n];
    if (c > CAP) c = CAP;
    int S = 512;
    while (S < c) S <<= 1;     // S in {512..4096}
    for (int i = tid; i < S; i += 1024)
        keys[i] = (i < c) ? cand[n * CAP + i] : 0ULL;
    __syncthreads();
    for (int k = 2; k <= S; k <<= 1) {
        for (int j = k >> 1; j > 0; j >>= 1) {
            for (int i = tid; i < S; i += 1024) {
                int l = i ^ j;
                if (l > i) {
                    unsigned long long a = keys[i], b = keys[l];
                    bool up = ((i & k) == 0);
                    if ((a > b) == up) { keys[i] = b; keys[l] = a; }
                }
            }
            __syncthreads();
        }
    }
    for (int r = tid; r < KTOP; r += 1024)
        s_skey[r] = keys[S - 1 - r];
    __syncthreads();

    // ---------- P2: zero sup bits (reuses keys) + decode (2 threads/candidate) ----------
    for (int i = tid; i < 7 * 7 * 64 * 2; i += 1024) sup32[i] = 0u;
    if (tid < 2 * KTOP) {
        const int r = tid >> 1, half = tid & 1;
        unsigned long long kk = s_skey[r];
        if (kk == 0ULL) {
            if (half == 0) {
                s_val[r] = 0; s_sc[r] = 0.0f; s_lab[r] = 0; s_area[r] = 0.0f;
                s_cx[r] = 0.0f; s_cy[r] = 0.0f; s_rad[r] = 0.0f;
                for (int q = 0; q < 8; ++q) s_cor[r * 8 + q] = 0.0f;
            }
        } else {
            unsigned int idx = ~((unsigned int)kk);
            int loc = (int)(idx / 15u);
            // angle argmax (first max): this thread scans 45 bins, partner the other 45
            const float* ap = ang + ((size_t)n * NANG) * HW + loc;
            float bv = -INFINITY; int bb = 1000;
            for (int k2 = 0; k2 < 45; ++k2) {
                int b = half * 45 + k2;
                float v = ap[(size_t)b * HW];
                if (v > bv) { bv = v; bb = b; }     // ascending: keeps first max
            }
            float ov = __shfl_xor(bv, 1);
            int   ob = __shfl_xor(bb, 1);
            if (ov > bv || (ov == bv && ob < bb)) { bv = ov; bb = ob; }
            if (half == 0) {
                int cl = (int)(idx % 15u);
                float topv = __uint_as_float((unsigned int)(kk >> 32));
                const float* rp = reg + ((size_t)n * 4) * HW + loc;
                float dx = rp[0] / 10.0f;
                float dy = rp[HW] / 10.0f;
                float dw = rp[2 * (size_t)HW] / 5.0f;
                float dh = rp[3 * (size_t)HW] / 5.0f;
                dw = fminf(fmaxf(dw, -10.0f), 4.0f);
                dh = fminf(fmaxf(dh, -10.0f), 4.0f);
                const float* an = anchors + ((size_t)n * HW + loc) * 5;
                float acx = an[0], acy = an[1], aw = an[2], ah = an[3];
                float bcx = dx * aw + acx;
                float bcy = dy * ah + acy;
                float bw = aw * expf(dw);
                float bh = ah * expf(dh);
                float pa = (float)bb - 90.0f;
                float th = pa * (float)0.017453292519943295;
                float cth = cosf(th), sth = sinf(th);
                float hw2 = bw * 0.5f, hh2 = bh * 0.5f;
                const float oxs[4] = {1.0f, -1.0f, -1.0f, 1.0f};
                const float oys[4] = {1.0f, 1.0f, -1.0f, -1.0f};
                for (int q = 0; q < 4; ++q) {
                    float ox = oxs[q] * hw2, oy = oys[q] * hh2;
                    s_cor[r * 8 + 2 * q]     = bcx + ox * cth - oy * sth;
                    s_cor[r * 8 + 2 * q + 1] = bcy + ox * sth + oy * cth;
                }
                s_val[r] = 1;
                s_sc[r] = sqrtf(topv);
                s_lab[r] = cl + 1;
                s_area[r] = bw * bh;
                s_cx[r] = bcx; s_cy[r] = bcy;
                s_rad[r] = 0.5f * sqrtf(bw * bw + bh * bh);
            }
        }
    }
    __syncthreads();

    // ---------- P3: pair IoU (inline prefilter) -> sup bits in LDS ----------
    for (int p = tid; p < KTOP * KTOP; p += 1024) {
        int i = p / KTOP;
        int j = p - i * KTOP;
        if (j <= i) continue;
        int li = s_lab[i];
        if (li == 0 || s_lab[j] != li) continue;
        float dx = s_cx[i] - s_cx[j], dy = s_cy[i] - s_cy[j];
        float rr = s_rad[i] + s_rad[j];
        if (dx * dx + dy * dy > rr * rr) continue;  // provably disjoint -> iou==0
        float cix[4], ciy[4], cjx[4], cjy[4];
        for (int q = 0; q < 4; ++q) {
            cix[q] = s_cor[i * 8 + 2 * q]; ciy[q] = s_cor[i * 8 + 2 * q + 1];
            cjx[q] = s_cor[j * 8 + 2 * q]; cjy[q] = s_cor[j * 8 + 2 * q + 1];
        }
        float inter = quad_inter_area(cix, ciy, cjx, cjy);
        float iou = inter / (s_area[i] + s_area[j] - inter + 1e-7f);
        if (iou > 0.4f) {
            // row i suppresses col j: cm[t=j>>6][rb=i>>6], lane j&63, bit i&63
            int base = (((j >> 6) * 7 + (i >> 6)) * 64 + (j & 63)) * 2 + ((i >> 5) & 1);
            atomicOr(&sup32[base], 1u << (i & 31));
        }
    }
    __syncthreads();

    // ---------- P4: greedy NMS on wave 0, register-resident ----------
    if (tid < 64) {
        const int l = tid;
        unsigned removed = 0;
#pragma unroll
        for (int t = 0; t < 7; ++t) {
            int r = 64 * t + l;
            int v = (r < KTOP) ? s_val[r] : 0;
            if (!v) removed |= (1u << t);
        }
        unsigned long long cm[7][7];
#pragma unroll
        for (int t = 0; t < 7; ++t)
#pragma unroll
            for (int rb = 0; rb < 7; ++rb) {
                int bi = ((t * 7 + rb) * 64 + l) * 2;
                cm[t][rb] = (unsigned long long)sup32[bi] |
                            ((unsigned long long)sup32[bi + 1] << 32);
            }
#pragma unroll
        for (int rb = 0; rb < 7; ++rb) {
            const int lim = (rb == 6) ? (KTOP - 384) : 64;
            for (int ib = 0; ib < lim; ++ib) {
                unsigned rm = (unsigned)__builtin_amdgcn_readlane((int)removed, ib);
                if (!((rm >> rb) & 1u)) {
                    removed |= ((unsigned)((cm[0][rb] >> ib) & 1ULL));
                    removed |= ((unsigned)((cm[1][rb] >> ib) & 1ULL)) << 1;
                    removed |= ((unsigned)((cm[2][rb] >> ib) & 1ULL)) << 2;
                    removed |= ((unsigned)((cm[3][rb] >> ib) & 1ULL)) << 3;
                    removed |= ((unsigned)((cm[4][rb] >> ib) & 1ULL)) << 4;
                    removed |= ((unsigned)((cm[5][rb] >> ib) & 1ULL)) << 5;
                    removed |= ((unsigned)((cm[6][rb] >> ib) & 1ULL)) << 6;
                }
            }
        }
        int rank = 0;
#pragma unroll
        for (int t = 0; t < 7; ++t) {
            bool kb = !((removed >> t) & 1u) && (64 * t + l < KTOP);
            unsigned long long m = __ballot(kb);
            int my = rank + __popcll(m & ((1ULL << l) - 1ULL));
            if (kb && my < POSTN) s_order[my] = 64 * t + l;
            rank += __popcll(m);
        }
        if (l == 0) s_kcnt = (rank < POSTN) ? rank : POSTN;
    }
    __syncthreads();

    // ---------- P5: output ----------
    const int kcnt = s_kcnt;
    for (int e = tid; e < POSTN * 11; e += 1024) {
        int r = e / 11, col = e - r * 11;
        float v = 0.0f;
        if (r < kcnt) {
            int i = s_order[r];
            if (col < 8)        v = s_cor[i * 8 + col];
            else if (col == 8)  v = s_sc[i];
            else if (col == 9)  v = (float)s_lab[i];
            else                v = 1.0f;
        }
        out[(n * POSTN + r) * 11 + col] = v;
    }
}

extern "C" void kernel_launch(void* const* d_in, const int* in_sizes, int n_in,
                              void* d_out, int out_size, void* d_ws, size_t ws_size,
                              hipStream_t stream) {
    const float* box_cls = (const float*)d_in[0];
    const float* box_reg = (const float*)d_in[1];
    const float* ctr     = (const float*)d_in[2];
    const float* ang     = (const float*)d_in[3];
    const float* anchors = (const float*)d_in[4];
    float* out = (float*)d_out;
    char* ws = (char*)d_ws;

    int* hist = (int*)(ws + HIST_OFF);
    int* cnt  = (int*)(ws + CNT_OFF);
    unsigned long long* cand = (unsigned long long*)(ws + CAND_OFF);

    hipMemsetAsync(d_ws, 0, ZERO_BYTES, stream);
    k_hist   <<<dim3(HW / 1024, NIMG), 256, 0, stream>>>(box_cls, ctr, hist);
    k_collect<<<dim3(HW / 1024, NIMG), 256, 0, stream>>>(box_cls, ctr, hist, cnt, cand);
    k_tail   <<<NIMG, 1024, 0, stream>>>(cand, cnt, box_reg, ang, anchors, out);
}

// Round 8
// 247.942 us; speedup vs baseline: 1.4037x; 1.4037x over previous
//
#include <hip/hip_runtime.h>
#include <math.h>

#define NIMG 4
#define NCLS 15
#define HW 65536
#define NANG 90
#define KTOP 400
#define POSTN 100
#define NBINS 4096
#define CAP 4096

// ---- workspace layout (bytes) ----
// zeroed: hist 4*4096*4=65536 | cnt 64 | supT 4*7*7*64*8=100352
#define HIST_OFF   0
#define CNT_OFF    65536
#define SUPT_OFF   65600
#define ZERO_BYTES 165952                 // = SUPT_OFF + 100352
#define CAND_OFF   165952                 // 4*4096*8 = 131072
#define SKEY_OFF   297024                 // 4*400*8
#define COR_OFF    309824                 // 4*400*8*4
#define AREA_OFF   361024                 // 6400 each below
#define LAB_OFF    367424
#define SC_OFF     373824
#define VAL_OFF    380224
#define CCX_OFF    386624
#define CCY_OFF    393024
#define CRAD_OFF   399424                 // end 405824

__device__ __forceinline__ float sigmoidf(float x) {
    return 1.0f / (1.0f + expf(-x));
}

// ---------------- K1: histogram of comb scores (float2, 2048 waves) ----------------
__global__ __launch_bounds__(256)
void k_hist(const float* __restrict__ cls, const float* __restrict__ ctr,
            int* __restrict__ hist) {
    __shared__ int sh[NBINS];
    const int n = blockIdx.y;
    const int p2 = (blockIdx.x * 256 + threadIdx.x) * 2;
    for (int b = threadIdx.x; b < NBINS; b += 256) sh[b] = 0;
    __syncthreads();
    float2 cv2 = *(const float2*)(ctr + n * HW + p2);
    float cv[2] = {sigmoidf(cv2.x), sigmoidf(cv2.y)};
    for (int j = 0; j < NCLS; ++j) {
        float2 s2 = *(const float2*)(cls + (size_t)(n * NCLS + j) * HW + p2);
        float sv[2] = {s2.x, s2.y};
#pragma unroll
        for (int e = 0; e < 2; ++e) {
            float s = sigmoidf(sv[e]);
            if (s > 0.05f) {
                float comb = s * cv[e];
                int b = (int)(comb * 4096.0f);
                b = b < 0 ? 0 : (b > NBINS - 1 ? NBINS - 1 : b);
                atomicAdd(&sh[b], 1);
            }
        }
    }
    __syncthreads();
    for (int b = threadIdx.x; b < NBINS; b += 256) {
        int v = sh[b];
        if (v) atomicAdd(&hist[n * NBINS + b], v);
    }
}

// ---------------- K2: parallel threshold + collect (float2, 2048 waves) ----------------
__global__ __launch_bounds__(256)
void k_collect(const float* __restrict__ cls, const float* __restrict__ ctr,
               const int* __restrict__ hist, int* __restrict__ cnt,
               unsigned long long* __restrict__ cand) {
    const int n = blockIdx.y;
    __shared__ int part[256];
    __shared__ int s_t;
    {
        const int* hb = hist + n * NBINS;
        int s = 0;
        int base = threadIdx.x * 16;
        for (int b = 0; b < 16; ++b) s += hb[base + b];
        part[threadIdx.x] = s;
        if (threadIdx.x == 0) s_t = 0;
        __syncthreads();
        // suffix sum: part[sg] = sum of segment sums sg..255
        for (int off = 1; off < 256; off <<= 1) {
            int v = part[threadIdx.x] +
                    ((threadIdx.x + off < 256) ? part[threadIdx.x + off] : 0);
            __syncthreads();
            part[threadIdx.x] = v;
            __syncthreads();
        }
        // my segment is the threshold segment if suffix >= KTOP and next suffix < KTOP
        int sg = threadIdx.x;
        int suf = part[sg];
        int above = (sg == 255) ? 0 : part[sg + 1];
        if (suf >= KTOP && above < KTOP) {
            int a2 = above, t = sg * 16;
            for (int b = sg * 16 + 15; b >= sg * 16; --b) {
                a2 += hb[b];
                if (a2 >= KTOP) { t = b; break; }
            }
            s_t = t;            // exactly one thread writes (suffix is non-increasing)
        }
        __syncthreads();
    }
    const int t = s_t;
    const int p2 = (blockIdx.x * 256 + threadIdx.x) * 2;
    float2 cv2 = *(const float2*)(ctr + n * HW + p2);
    float cv[2] = {sigmoidf(cv2.x), sigmoidf(cv2.y)};
    for (int j = 0; j < NCLS; ++j) {
        float2 s2 = *(const float2*)(cls + (size_t)(n * NCLS + j) * HW + p2);
        float sv[2] = {s2.x, s2.y};
#pragma unroll
        for (int e = 0; e < 2; ++e) {
            float s = sigmoidf(sv[e]);
            if (s > 0.05f) {
                float comb = s * cv[e];
                int b = (int)(comb * 4096.0f);
                b = b < 0 ? 0 : (b > NBINS - 1 ? NBINS - 1 : b);
                if (b >= t) {
                    int pos = atomicAdd(&cnt[n], 1);
                    if (pos < CAP) {
                        unsigned int fb  = __float_as_uint(comb);
                        unsigned int idx = (unsigned int)((p2 + e) * NCLS + j);
                        cand[n * CAP + pos] =
                            ((unsigned long long)fb << 32) | (unsigned long long)(~idx);
                    }
                }
            }
        }
    }
}

// ---------------- K3: bitonic sort -> top-400 keys ----------------
__global__ __launch_bounds__(256)
void k_select(const unsigned long long* __restrict__ cand, const int* __restrict__ cnt,
              unsigned long long* __restrict__ skey) {
    const int n = blockIdx.x;
    __shared__ unsigned long long key[CAP];
    int c = cnt[n];
    if (c > CAP) c = CAP;
    int S = 512;
    while (S < c) S <<= 1;     // S in {512..4096}, >= max(c, KTOP)
    for (int t = threadIdx.x; t < S; t += 256)
        key[t] = (t < c) ? cand[n * CAP + t] : 0ULL;
    __syncthreads();
    for (int k = 2; k <= S; k <<= 1) {
        for (int j = k >> 1; j > 0; j >>= 1) {
            for (int i = threadIdx.x; i < S; i += 256) {
                int l = i ^ j;
                if (l > i) {
                    unsigned long long a = key[i], b = key[l];
                    bool up = ((i & k) == 0);
                    if ((a > b) == up) { key[i] = b; key[l] = a; }
                }
            }
            __syncthreads();
        }
    }
    for (int r = threadIdx.x; r < KTOP; r += 256)
        skey[n * KTOP + r] = key[S - 1 - r];
}

// ---------------- K4: per-candidate decode (one wave each) ----------------
__global__ __launch_bounds__(64)
void k_decode(const unsigned long long* __restrict__ skey,
              const float* __restrict__ reg, const float* __restrict__ ang,
              const float* __restrict__ anchors,
              float* __restrict__ cor, float* __restrict__ area, int* __restrict__ lab,
              float* __restrict__ sc, int* __restrict__ val,
              float* __restrict__ ccx, float* __restrict__ ccy, float* __restrict__ crad) {
#pragma clang fp contract(off)
    const int r = blockIdx.x;
    const int n = blockIdx.y;
    const int l = threadIdx.x;
    const int base = n * KTOP + r;
    unsigned long long kk = skey[base];
    if (kk == 0ULL) {
        if (l == 0) {
            val[base] = 0; sc[base] = 0.0f; lab[base] = 0; area[base] = 0.0f;
            ccx[base] = 0.0f; ccy[base] = 0.0f; crad[base] = 0.0f;
            for (int q = 0; q < 8; ++q) cor[base * 8 + q] = 0.0f;
        }
        return;
    }
    unsigned int idx = ~((unsigned int)kk);
    int loc = (int)(idx / 15u);
    // angle argmax (first max) across the wave
    const float* ap = ang + ((size_t)n * NANG) * HW + loc;
    float bv = -INFINITY; int bb = 1000;
    for (int b = l; b < NANG; b += 64) {
        float v = ap[(size_t)b * HW];
        if (v > bv) { bv = v; bb = b; }   // b ascending per lane: keeps first max
    }
    for (int off = 32; off > 0; off >>= 1) {
        float ov = __shfl_down(bv, off);
        int   ob = __shfl_down(bb, off);
        if (ov > bv || (ov == bv && ob < bb)) { bv = ov; bb = ob; }
    }
    if (l == 0) {
        int cl = (int)(idx % 15u);
        float topv = __uint_as_float((unsigned int)(kk >> 32));
        const float* rp = reg + ((size_t)n * 4) * HW + loc;
        float dx = rp[0] / 10.0f;
        float dy = rp[HW] / 10.0f;
        float dw = rp[2 * (size_t)HW] / 5.0f;
        float dh = rp[3 * (size_t)HW] / 5.0f;
        dw = fminf(fmaxf(dw, -10.0f), 4.0f);
        dh = fminf(fmaxf(dh, -10.0f), 4.0f);
        const float* an = anchors + ((size_t)n * HW + loc) * 5;
        float acx = an[0], acy = an[1], aw = an[2], ah = an[3];
        float bcx = dx * aw + acx;
        float bcy = dy * ah + acy;
        float bw = aw * expf(dw);
        float bh = ah * expf(dh);
        float pa = (float)bb - 90.0f;
        float th = pa * (float)0.017453292519943295;
        float cth = cosf(th), sth = sinf(th);
        float hw2 = bw * 0.5f, hh2 = bh * 0.5f;
        const float oxs[4] = {1.0f, -1.0f, -1.0f, 1.0f};
        const float oys[4] = {1.0f, 1.0f, -1.0f, -1.0f};
        for (int q = 0; q < 4; ++q) {
            float ox = oxs[q] * hw2, oy = oys[q] * hh2;
            cor[base * 8 + 2 * q]     = bcx + ox * cth - oy * sth;
            cor[base * 8 + 2 * q + 1] = bcy + ox * sth + oy * cth;
        }
        val[base] = 1;
        sc[base] = sqrtf(topv);
        lab[base] = cl + 1;
        area[base] = bw * bh;
        ccx[base] = bcx; ccy[base] = bcy;
        crad[base] = 0.5f * sqrtf(bw * bw + bh * bh);
    }
}

// ---- register-resident dynamic-index helpers (avoid scratch) ----
__device__ __forceinline__ float arr_get8(const float* a, int idx) {
    float r = a[0];
#pragma unroll
    for (int s = 1; s < 8; ++s) r = (s == idx) ? a[s] : r;
    return r;
}
__device__ __forceinline__ void arr_set8(float* a, int idx, float v) {
#pragma unroll
    for (int s = 0; s < 8; ++s) a[s] = (s == idx) ? v : a[s];
}

// ---------------- rotated-quad intersection (Sutherland-Hodgman, mirrors ref) ----
__device__ float quad_inter_area(const float* c1x, const float* c1y,
                                 const float* c2x, const float* c2y) {
#pragma clang fp contract(off)
    float px[8], py[8], qx[8], qy[8];
    int n = 4;
#pragma unroll
    for (int i = 0; i < 8; ++i) { px[i] = (i < 4) ? c1x[i] : 0.0f;
                                  py[i] = (i < 4) ? c1y[i] : 0.0f;
                                  qx[i] = 0.0f; qy[i] = 0.0f; }
#pragma unroll
    for (int e = 0; e < 4; ++e) {
        float p1x = c2x[e], p1y = c2y[e];
        int e2 = (e + 1) & 3;
        float ex = c2x[e2] - p1x, ey = c2y[e2] - p1y;
        int m = 0;
#pragma unroll
        for (int i = 0; i < 8; ++i) {
            if (i < n) {
                int j = (i == n - 1) ? 0 : i + 1;
                float cxi = px[i], cyi = py[i];
                float cxj = arr_get8(px, j), cyj = arr_get8(py, j);
                float dc = ex * (cyi - p1y) - ey * (cxi - p1x);
                float dn = ex * (cyj - p1y) - ey * (cxj - p1x);
                bool ic = (dc >= 0.0f), in2 = (dn >= 0.0f);
                if (ic) { arr_set8(qx, m, cxi); arr_set8(qy, m, cyi); ++m; }
                if (ic != in2) {
                    float denom = dc - dn;
                    if (fabsf(denom) < 1e-8f) denom = 1e-8f;
                    float tp = dc / denom;
                    arr_set8(qx, m, cxi + tp * (cxj - cxi));
                    arr_set8(qy, m, cyi + tp * (cyj - cyi));
                    ++m;
                }
            }
        }
        n = m;
        if (n == 0) return 0.0f;
#pragma unroll
        for (int i = 0; i < 8; ++i) { px[i] = qx[i]; py[i] = qy[i]; }
    }
    float ssum = 0.0f;
#pragma unroll
    for (int i = 0; i < 8; ++i) {
        if (i < n) {
            int j = (i == n - 1) ? 0 : i + 1;
            ssum += px[i] * arr_get8(py, j) - arr_get8(px, j) * py[i];
        }
    }
    return 0.5f * fabsf(ssum);
}

// ---------------- K5: fused prefilter + IoU -> transposed suppress bits ----------------
__global__ __launch_bounds__(256)
void k_pairs(const float* __restrict__ cor, const float* __restrict__ area,
             const int* __restrict__ lab,
             const float* __restrict__ ccx, const float* __restrict__ ccy,
             const float* __restrict__ crad,
             unsigned long long* __restrict__ supT) {
#pragma clang fp contract(off)
    const int n = blockIdx.y;
    const int p = blockIdx.x * 256 + threadIdx.x;
    if (p >= KTOP * KTOP) return;
    const int i = p / KTOP;
    const int j = p - i * KTOP;
    if (j <= i) return;
    const int base = n * KTOP;
    const int li = lab[base + i];
    if (li == 0 || lab[base + j] != li) return;
    float dx = ccx[base + i] - ccx[base + j];
    float dy = ccy[base + i] - ccy[base + j];
    float rr = crad[base + i] + crad[base + j];
    if (dx * dx + dy * dy > rr * rr) return;   // provably disjoint -> inter==0 -> iou==0
    float cix[4], ciy[4], cjx[4], cjy[4];
    for (int q = 0; q < 4; ++q) {
        cix[q] = cor[(base + i) * 8 + 2 * q]; ciy[q] = cor[(base + i) * 8 + 2 * q + 1];
        cjx[q] = cor[(base + j) * 8 + 2 * q]; cjy[q] = cor[(base + j) * 8 + 2 * q + 1];
    }
    float inter = quad_inter_area(cix, ciy, cjx, cjy);
    float iou = inter / (area[base + i] + area[base + j] - inter + 1e-7f);
    if (iou > 0.4f) {
        // row i suppresses column j: bit (i&63) of supT[n][j>>6][i>>6][j&63]
        atomicOr(&supT[((size_t)(n * 7 + (j >> 6)) * 7 + (i >> 6)) * 64 + (j & 63)],
                 1ULL << (i & 63));
    }
}

// ---------------- K6: single-wave register-resident greedy NMS + output ----------------
__global__ __launch_bounds__(64)
void k_nms_out(const unsigned long long* __restrict__ supT,
               const int* __restrict__ val,
               const float* __restrict__ cor, const float* __restrict__ sc,
               const int* __restrict__ lab, float* __restrict__ out) {
    const int n = blockIdx.x;
    const int l = threadIdx.x;
    // lane l owns columns (candidates) l, l+64, ..., l+384; bit t of `removed`
    unsigned removed = 0;
#pragma unroll
    for (int t = 0; t < 7; ++t) {
        int r = 64 * t + l;
        int v = (r < KTOP) ? val[n * KTOP + r] : 0;
        if (!v) removed |= (1u << t);
    }
    // cm[t][rb] bit ib = row (64*rb+ib) suppresses col (64*t+l)
    unsigned long long cm[7][7];
#pragma unroll
    for (int t = 0; t < 7; ++t)
#pragma unroll
        for (int rb = 0; rb < 7; ++rb)
            cm[t][rb] = supT[((size_t)(n * 7 + t) * 7 + rb) * 64 + l];
    // serial greedy scan, all in registers
#pragma unroll
    for (int rb = 0; rb < 7; ++rb) {
        const int lim = (rb == 6) ? (KTOP - 384) : 64;
        for (int ib = 0; ib < lim; ++ib) {
            unsigned rm = (unsigned)__builtin_amdgcn_readlane((int)removed, ib);
            if (!((rm >> rb) & 1u)) {   // candidate 64*rb+ib kept -> apply its suppressions
                removed |= ((unsigned)((cm[0][rb] >> ib) & 1ULL));
                removed |= ((unsigned)((cm[1][rb] >> ib) & 1ULL)) << 1;
                removed |= ((unsigned)((cm[2][rb] >> ib) & 1ULL)) << 2;
                removed |= ((unsigned)((cm[3][rb] >> ib) & 1ULL)) << 3;
                removed |= ((unsigned)((cm[4][rb] >> ib) & 1ULL)) << 4;
                removed |= ((unsigned)((cm[5][rb] >> ib) & 1ULL)) << 5;
                removed |= ((unsigned)((cm[6][rb] >> ib) & 1ULL)) << 6;
            }
        }
    }
    // rank kept candidates in index order, collect first 100
    __shared__ int order[POSTN];
    int rank = 0;
#pragma unroll
    for (int t = 0; t < 7; ++t) {
        bool kb = !((removed >> t) & 1u) && (64 * t + l < KTOP);
        unsigned long long m = __ballot(kb);
        int my = rank + __popcll(m & ((1ULL << l) - 1ULL));
        if (kb && my < POSTN) order[my] = 64 * t + l;
        rank += __popcll(m);
    }
    int kcnt = rank < POSTN ? rank : POSTN;
    __syncthreads();   // single wave: cheap; makes order[] visible
    for (int e = l; e < POSTN * 11; e += 64) {
        int r = e / 11, c = e - r * 11;
        float v = 0.0f;
        if (r < kcnt) {
            int i = order[r];
            int b = n * KTOP + i;
            if (c < 8)       v = cor[b * 8 + c];
            else if (c == 8) v = sc[b];
            else if (c == 9) v = (float)lab[b];
            else             v = 1.0f;
        }
        out[(n * POSTN + r) * 11 + c] = v;
    }
}

extern "C" void kernel_launch(void* const* d_in, const int* in_sizes, int n_in,
                              void* d_out, int out_size, void* d_ws, size_t ws_size,
                              hipStream_t stream) {
    const float* box_cls = (const float*)d_in[0];
    const float* box_reg = (const float*)d_in[1];
    const float* ctr     = (const float*)d_in[2];
    const float* ang     = (const float*)d_in[3];
    const float* anchors = (const float*)d_in[4];
    float* out = (float*)d_out;
    char* ws = (char*)d_ws;

    int* hist = (int*)(ws + HIST_OFF);
    int* cnt  = (int*)(ws + CNT_OFF);
    unsigned long long* supT = (unsigned long long*)(ws + SUPT_OFF);
    unsigned long long* cand = (unsigned long long*)(ws + CAND_OFF);
    unsigned long long* skey = (unsigned long long*)(ws + SKEY_OFF);
    float* cor  = (float*)(ws + COR_OFF);
    float* area = (float*)(ws + AREA_OFF);
    int* lab    = (int*)(ws + LAB_OFF);
    float* sc   = (float*)(ws + SC_OFF);
    int* val    = (int*)(ws + VAL_OFF);
    float* ccx  = (float*)(ws + CCX_OFF);
    float* ccy  = (float*)(ws + CCY_OFF);
    float* crad = (float*)(ws + CRAD_OFF);

    hipMemsetAsync(d_ws, 0, ZERO_BYTES, stream);
    k_hist   <<<dim3(HW / 512, NIMG), 256, 0, stream>>>(box_cls, ctr, hist);
    k_collect<<<dim3(HW / 512, NIMG), 256, 0, stream>>>(box_cls, ctr, hist, cnt, cand);
    k_select <<<NIMG, 256, 0, stream>>>(cand, cnt, skey);
    k_decode <<<dim3(KTOP, NIMG), 64, 0, stream>>>(skey, box_reg, ang, anchors,
                                                   cor, area, lab, sc, val, ccx, ccy, crad);
    k_pairs  <<<dim3((KTOP * KTOP + 255) / 256, NIMG), 256, 0, stream>>>(
                 cor, area, lab, ccx, ccy, crad, supT);
    k_nms_out<<<NIMG, 64, 0, stream>>>(supT, val, cor, sc, lab, out);
}